// Round 4
// baseline (477.605 us; speedup 1.0000x reference)
//
#include <hip/hip_runtime.h>
#include <math.h>

#define B 2
#define S 1024
#define E 2048
#define H 16
#define HD 128
#define ROT 64
#define EPSN 1e-12f

using half8 = __attribute__((ext_vector_type(8))) _Float16;
using half4 = __attribute__((ext_vector_type(4))) _Float16;
using half2 = __attribute__((ext_vector_type(2))) _Float16;
using f32x4 = __attribute__((ext_vector_type(4))) float;

__device__ inline uint4 cvt_f32x8_f16x8(float4 a, float4 b) {
    half8 h;
    h[0] = (_Float16)a.x; h[1] = (_Float16)a.y; h[2] = (_Float16)a.z; h[3] = (_Float16)a.w;
    h[4] = (_Float16)b.x; h[5] = (_Float16)b.y; h[6] = (_Float16)b.z; h[7] = (_Float16)b.w;
    return *(uint4*)&h;
}

// ---------------------------------------------------------------------------
// Fused QKV NT-GEMM, convert-on-load fp32->fp16, MFMA 16x16x32_f16.
// 128x128 tile, BK=64, 256 thr (4 waves 2x2). blockIdx.z selects {wq,wk,wv}.
// n-block == one head (128 cols) -> writes (b,h,s,d) fp16 directly.
// A-frag: lane holds A[m=lane&15][k=(lane>>4)*8+j]; C/D: row=(lane>>4)*4+r,
// col=lane&15 (verified rounds 2-3).
// ---------------------------------------------------------------------------
__global__ __launch_bounds__(256) void gemm_qkv(const float* __restrict__ hs,
                                                const float* __restrict__ wq,
                                                const float* __restrict__ wk,
                                                const float* __restrict__ wv,
                                                _Float16* __restrict__ qo,
                                                _Float16* __restrict__ ko,
                                                _Float16* __restrict__ vo) {
    __shared__ uint4 As[8][128];   // As[kq][m] = fp16 A[mBase+m][k0+kq*8..+7]
    __shared__ uint4 Ws[8][128];
    const float* Wp = (blockIdx.z == 0) ? wq : (blockIdx.z == 1) ? wk : wv;
    _Float16*    C  = (blockIdx.z == 0) ? qo : (blockIdx.z == 1) ? ko : vo;
    const int tid  = threadIdx.x;
    const int lane = tid & 63;
    const int wave = tid >> 6;
    const int wm   = (wave >> 1) * 64;
    const int wn   = (wave & 1) * 64;
    const int l15  = lane & 15;
    const int lq   = lane >> 4;
    const int mBase = blockIdx.y * 128;        // over B*S
    const int h     = blockIdx.x;              // head
    const int nBase = h * 128;

    f32x4 acc[4][4];
#pragma unroll
    for (int mt = 0; mt < 4; ++mt)
#pragma unroll
        for (int nt = 0; nt < 4; ++nt)
            acc[mt][nt] = (f32x4){0.f, 0.f, 0.f, 0.f};

    for (int k0 = 0; k0 < E; k0 += 64) {
#pragma unroll
        for (int j = 0; j < 4; ++j) {
            int f = tid + j * 256;              // 128 m x 8 kq
            int m = f >> 3, kq = f & 7;
            const float4* pa = (const float4*)&hs[(size_t)(mBase + m) * E + k0 + kq * 8];
            const float4* pw = (const float4*)&Wp[(size_t)(nBase + m) * E + k0 + kq * 8];
            As[kq][m] = cvt_f32x8_f16x8(pa[0], pa[1]);
            Ws[kq][m] = cvt_f32x8_f16x8(pw[0], pw[1]);
        }
        __syncthreads();
#pragma unroll
        for (int ks = 0; ks < 2; ++ks) {
            half8 af[4], wf[4];
#pragma unroll
            for (int t = 0; t < 4; ++t) {
                af[t] = *(const half8*)&As[ks * 4 + lq][wm + t * 16 + l15];
                wf[t] = *(const half8*)&Ws[ks * 4 + lq][wn + t * 16 + l15];
            }
#pragma unroll
            for (int mt = 0; mt < 4; ++mt)
#pragma unroll
                for (int nt = 0; nt < 4; ++nt)
                    acc[mt][nt] = __builtin_amdgcn_mfma_f32_16x16x32_f16(
                        af[mt], wf[nt], acc[mt][nt], 0, 0, 0);
        }
        __syncthreads();
    }

    // write (b,h,s,d) fp16
#pragma unroll
    for (int mt = 0; mt < 4; ++mt)
#pragma unroll
        for (int nt = 0; nt < 4; ++nt)
#pragma unroll
            for (int r = 0; r < 4; ++r) {
                int row = mBase + wm + mt * 16 + lq * 4 + r;  // global s in B*S
                int d   = wn + nt * 16 + l15;
                int b = row >> 10, s = row & (S - 1);
                C[(((size_t)b * H + h) * S + s) * HD + d] = (_Float16)acc[mt][nt][r];
            }
}

// ---------------------------------------------------------------------------
// Out-projection NT-GEMM: A fp16 (b,s,E), W fp32 convert-on-load, out fp32.
// 128m x 64n tile, BK=64, 256 thr (4 waves: 64m x 32n each) -> 512 blocks.
// ---------------------------------------------------------------------------
__global__ __launch_bounds__(256) void gemm_out(const _Float16* __restrict__ A,
                                                const float* __restrict__ Wp,
                                                float* __restrict__ C) {
    __shared__ uint4 As[8][128];
    __shared__ uint4 Ws[8][64];
    const int tid  = threadIdx.x;
    const int lane = tid & 63;
    const int wave = tid >> 6;
    const int wm   = (wave >> 1) * 64;
    const int wn   = (wave & 1) * 32;
    const int l15  = lane & 15;
    const int lq   = lane >> 4;
    const int mBase = blockIdx.y * 128;
    const int nBase = blockIdx.x * 64;

    f32x4 acc[4][2];
#pragma unroll
    for (int mt = 0; mt < 4; ++mt)
#pragma unroll
        for (int nt = 0; nt < 2; ++nt)
            acc[mt][nt] = (f32x4){0.f, 0.f, 0.f, 0.f};

    for (int k0 = 0; k0 < E; k0 += 64) {
#pragma unroll
        for (int j = 0; j < 4; ++j) {
            int f = tid + j * 256;
            int m = f >> 3, kq = f & 7;
            As[kq][m] = *(const uint4*)&A[(size_t)(mBase + m) * E + k0 + kq * 8];
        }
#pragma unroll
        for (int j = 0; j < 2; ++j) {
            int f = tid + j * 256;              // 64 n x 8 kq
            int n = f >> 3, kq = f & 7;
            const float4* pw = (const float4*)&Wp[(size_t)(nBase + n) * E + k0 + kq * 8];
            Ws[kq][n] = cvt_f32x8_f16x8(pw[0], pw[1]);
        }
        __syncthreads();
#pragma unroll
        for (int ks = 0; ks < 2; ++ks) {
            half8 af[4], wf[2];
#pragma unroll
            for (int t = 0; t < 4; ++t)
                af[t] = *(const half8*)&As[ks * 4 + lq][wm + t * 16 + l15];
#pragma unroll
            for (int t = 0; t < 2; ++t)
                wf[t] = *(const half8*)&Ws[ks * 4 + lq][wn + t * 16 + l15];
#pragma unroll
            for (int mt = 0; mt < 4; ++mt)
#pragma unroll
                for (int nt = 0; nt < 2; ++nt)
                    acc[mt][nt] = __builtin_amdgcn_mfma_f32_16x16x32_f16(
                        af[mt], wf[nt], acc[mt][nt], 0, 0, 0);
        }
        __syncthreads();
    }

#pragma unroll
    for (int mt = 0; mt < 4; ++mt)
#pragma unroll
        for (int nt = 0; nt < 2; ++nt)
#pragma unroll
            for (int r = 0; r < 4; ++r) {
                int row = mBase + wm + mt * 16 + lq * 4 + r;
                int col = nBase + wn + nt * 16 + l15;
                C[(size_t)row * E + col] = acc[mt][nt][r];
            }
}

// ---------------------------------------------------------------------------
// counts[b][s] = inclusive prefix of (mask==0)
// ---------------------------------------------------------------------------
__global__ __launch_bounds__(1024) void counts_kernel(const float* __restrict__ am,
                                                      float* __restrict__ counts) {
    __shared__ float buf[S];
    const int b = blockIdx.x, t = threadIdx.x;
    buf[t] = (am[b * S + t] == 0.f) ? 1.f : 0.f;
    __syncthreads();
    for (int off = 1; off < S; off <<= 1) {
        float add = (t >= off) ? buf[t - off] : 0.f;
        __syncthreads();
        buf[t] += add;
        __syncthreads();
    }
    counts[b * S + t] = buf[t];
}

// ---------------------------------------------------------------------------
// Rotary + L2 normalize + mask, in-place on fp16 (b,h,s,d).
// One wave per (b,h,s); lane l handles dims 2l, 2l+1.
// ---------------------------------------------------------------------------
__global__ __launch_bounds__(256) void rotary_norm(_Float16* __restrict__ qh,
                                                   _Float16* __restrict__ kh,
                                                   const float* __restrict__ am,
                                                   const int* __restrict__ pos) {
    const int wave = threadIdx.x >> 6;
    const int lane = threadIdx.x & 63;
    const int item = blockIdx.x * 4 + wave;      // < B*H*S
    const int b = item / (H * S);
    const int h = (item / S) % H;
    const int s = item % S;

    const float p = (float)pos[b * S + s];
    float co = 1.f, si = 0.f;
    if (lane < 32) {
        float ang = p * expf(-0.28782313662425574f * (float)lane); // ln(10000)/32
        sincosf(ang, &si, &co);
    }
    const float valid = (am[b * S + s] == 0.f) ? 1.f : 0.f;
    const size_t base = ((size_t)(b * H + h) * S + s) * HD;

    _Float16* bufs[2] = {qh, kh};
#pragma unroll
    for (int a = 0; a < 2; ++a) {
        _Float16* ptr = bufs[a];
        half2 xin = *(const half2*)&ptr[base + 2 * lane];
        float x0 = (float)xin[0], x1 = (float)xin[1];
        float y0, y1;
        if (lane < 32) {
            y0 = x0 * co - x1 * si;
            y1 = x1 * co + x0 * si;
        } else {
            y0 = x0;
            y1 = x1;
        }
        float ss = y0 * y0 + y1 * y1;
#pragma unroll
        for (int off = 32; off > 0; off >>= 1)
            ss += __shfl_xor(ss, off);
        float scale = valid / fmaxf(sqrtf(ss), EPSN);
        half2 xo;
        xo[0] = (_Float16)(y0 * scale);
        xo[1] = (_Float16)(y1 * scale);
        *(half2*)&ptr[base + 2 * lane] = xo;
    }
}

// ---------------------------------------------------------------------------
// vprep: v (b,h,s,d) fp16 -> scaled V^T (b,h,d,s) fp16.
// scale = mask / max(counts^sigmoid(nc[h]), 1). 64-s tiles.
// ---------------------------------------------------------------------------
__global__ __launch_bounds__(256) void vprep(const _Float16* __restrict__ v,
                                             _Float16* __restrict__ vt,
                                             const float* __restrict__ am,
                                             const float* __restrict__ counts,
                                             const float* __restrict__ nc) {
    __shared__ _Float16 T[HD][72];     // [d][s] pad 8
    __shared__ float sscale[64];
    const int bh = blockIdx.y;
    const int b = bh >> 4, h = bh & 15;
    const int s0 = blockIdx.x * 64;
    const int tid = threadIdx.x;

    if (tid < 64) {
        int s = s0 + tid;
        float sig = 1.f / (1.f + expf(-nc[h]));
        float denom = fmaxf(powf(counts[b * S + s], sig), 1.f);
        float m = (am[b * S + s] == 0.f) ? 1.f : 0.f;
        sscale[tid] = m / denom;
    }
    __syncthreads();

#pragma unroll
    for (int j = 0; j < 4; ++j) {
        int f = tid + j * 256;
        int s = f >> 4, c8 = f & 15;
        half8 x = *(const half8*)&v[((size_t)bh * S + s0 + s) * HD + c8 * 8];
        float sc = sscale[s];
#pragma unroll
        for (int i = 0; i < 8; ++i)
            T[c8 * 8 + i][s] = (_Float16)((float)x[i] * sc);
    }
    __syncthreads();

#pragma unroll
    for (int j = 0; j < 4; ++j) {
        int f = tid + j * 256;
        int d = f >> 3, c8 = f & 7;
        *(uint4*)&vt[((size_t)bh * HD + d) * S + s0 + c8 * 8] =
            *(const uint4*)&T[d][c8 * 8];
    }
}

// ---------------------------------------------------------------------------
// MFMA attention with register prefetch of the next K/V chunk.
// qh,kh: (b,h,s,d); vt: (b,h,d,s); o: (b,s,E) fp16.
// Block = (b,h) x 64-q tile, 4 waves. K chunks of 64.
// ---------------------------------------------------------------------------
__global__ __launch_bounds__(256) void attn_mfma(const _Float16* __restrict__ qh,
                                                 const _Float16* __restrict__ kh,
                                                 const _Float16* __restrict__ vt,
                                                 _Float16* __restrict__ o) {
    __shared__ _Float16 Ks[64][136];   // [key][d], +8 pad
    __shared__ _Float16 Vs[HD][72];    // [d][key], +8 pad
    __shared__ _Float16 Ps[64][72];    // [q][key], +8 pad

    const int qt = (int)gridDim.x - 1 - (int)blockIdx.x;   // heavy first
    const int bh = blockIdx.y;
    const int b = bh >> 4, h = bh & 15;
    const int tid = threadIdx.x;
    const int lane = tid & 63;
    const int w = tid >> 6;
    const int l15 = lane & 15;
    const int lq = lane >> 4;
    const int qBase = qt * 64;
    const size_t sd_base = (size_t)bh * S * HD;

    // Q A-frags in registers
    half8 qf[4];
#pragma unroll
    for (int ks = 0; ks < 4; ++ks)
        qf[ks] = *(const half8*)&qh[sd_base + (size_t)(qBase + w * 16 + l15) * HD +
                                    ks * 32 + lq * 8];

    f32x4 oacc[8];
#pragma unroll
    for (int dt = 0; dt < 8; ++dt)
        oacc[dt] = (f32x4){0.f, 0.f, 0.f, 0.f};

    const int nkc = qt + 1;
    uint4 pk[4], pv[4];
    // prefetch chunk 0
#pragma unroll
    for (int j = 0; j < 4; ++j) {
        int f = tid + j * 256;
        int rK = f >> 4, c8K = f & 15;
        int rV = f >> 3, c8V = f & 7;
        pk[j] = *(const uint4*)&kh[sd_base + (size_t)rK * HD + c8K * 8];
        pv[j] = *(const uint4*)&vt[sd_base + (size_t)rV * S + c8V * 8];
    }

    for (int kc = 0; kc < nkc; ++kc) {
        __syncthreads();   // prev-iter Ks/Vs reads complete
#pragma unroll
        for (int j = 0; j < 4; ++j) {
            int f = tid + j * 256;
            int rK = f >> 4, c8K = f & 15;
            int rV = f >> 3, c8V = f & 7;
            *(uint4*)&Ks[rK][c8K * 8] = pk[j];
            *(uint4*)&Vs[rV][c8V * 8] = pv[j];
        }
        __syncthreads();

        // issue next chunk's loads; they fly during compute below
        if (kc + 1 < nkc) {
            const int kB = (kc + 1) * 64;
#pragma unroll
            for (int j = 0; j < 4; ++j) {
                int f = tid + j * 256;
                int rK = f >> 4, c8K = f & 15;
                int rV = f >> 3, c8V = f & 7;
                pk[j] = *(const uint4*)&kh[sd_base + (size_t)(kB + rK) * HD + c8K * 8];
                pv[j] = *(const uint4*)&vt[sd_base + (size_t)rV * S + kB + c8V * 8];
            }
        }

        const int kBase = kc * 64;
        // QK^T: 4 key-tiles x 4 k-steps
        f32x4 sacc[4];
#pragma unroll
        for (int nt = 0; nt < 4; ++nt)
            sacc[nt] = (f32x4){0.f, 0.f, 0.f, 0.f};
#pragma unroll
        for (int nt = 0; nt < 4; ++nt)
#pragma unroll
            for (int ks = 0; ks < 4; ++ks) {
                half8 kf = *(const half8*)&Ks[nt * 16 + l15][ks * 32 + lq * 8];
                sacc[nt] = __builtin_amdgcn_mfma_f32_16x16x32_f16(qf[ks], kf,
                                                                  sacc[nt], 0, 0, 0);
            }

        // causal mask + P to LDS (C-layout write, wave-local rows)
#pragma unroll
        for (int nt = 0; nt < 4; ++nt)
#pragma unroll
            for (int r = 0; r < 4; ++r) {
                int qg = qBase + w * 16 + lq * 4 + r;
                int kg = kBase + nt * 16 + l15;
                float sv = (kg <= qg) ? sacc[nt][r] : 0.f;
                Ps[w * 16 + lq * 4 + r][nt * 16 + l15] = (_Float16)sv;
            }

        // PV: A-frags from Ps (wave-local), B-frags from Vs rows (= d)
        half8 pf[2];
        pf[0] = *(const half8*)&Ps[w * 16 + l15][lq * 8];
        pf[1] = *(const half8*)&Ps[w * 16 + l15][32 + lq * 8];
#pragma unroll
        for (int dt = 0; dt < 8; ++dt)
#pragma unroll
            for (int ks = 0; ks < 2; ++ks) {
                half8 vf = *(const half8*)&Vs[dt * 16 + l15][ks * 32 + lq * 8];
                oacc[dt] = __builtin_amdgcn_mfma_f32_16x16x32_f16(pf[ks], vf,
                                                                  oacc[dt], 0, 0, 0);
            }
    }

    // write O (b,s,E) fp16
#pragma unroll
    for (int dt = 0; dt < 8; ++dt)
#pragma unroll
        for (int r = 0; r < 4; ++r) {
            size_t off = (size_t)(b * S + qBase + w * 16 + lq * 4 + r) * E +
                         h * HD + dt * 16 + l15;
            o[off] = (_Float16)oacc[dt][r];
        }
}

// ---------------------------------------------------------------------------
extern "C" void kernel_launch(void* const* d_in, const int* in_sizes, int n_in,
                              void* d_out, int out_size, void* d_ws, size_t ws_size,
                              hipStream_t stream) {
    (void)in_sizes; (void)n_in; (void)out_size; (void)ws_size;
    const float* hs = (const float*)d_in[0];
    const float* wq = (const float*)d_in[1];
    const float* wk = (const float*)d_in[2];
    const float* wv = (const float*)d_in[3];
    const float* wo = (const float*)d_in[4];
    const float* nc = (const float*)d_in[5];
    const float* am = (const float*)d_in[6];
    const int*  pos = (const int*)d_in[7];
    float* out = (float*)d_out;

    const size_t act = (size_t)B * S * E;           // 4,194,304
    _Float16* qhh = (_Float16*)d_ws;                // (b,h,s,d)
    _Float16* khh = qhh + act;
    _Float16* vhh = khh + act;                      // (b,h,s,d)
    _Float16* vtt = vhh + act;                      // (b,h,d,s)
    _Float16* abb = vtt + act;                      // attn out (b,s,E)
    float* cnt = (float*)(abb + act);               // B*S floats
    // total ws: 5 * 8.39MB + 8KB ~= 42 MB

    dim3 qkvgrid(H, (B * S) / 128, 3);              // 16 x 16 x 3 = 768 blocks
    gemm_qkv<<<qkvgrid, 256, 0, stream>>>(hs, wq, wk, wv, qhh, khh, vhh);

    counts_kernel<<<B, S, 0, stream>>>(am, cnt);
    rotary_norm<<<(B * H * S) / 4, 256, 0, stream>>>(qhh, khh, am, pos);
    vprep<<<dim3(S / 64, B * H), 256, 0, stream>>>(vhh, vtt, am, cnt, nc);

    attn_mfma<<<dim3(S / 64, B * H), 256, 0, stream>>>(qhh, khh, vtt, abb);

    gemm_out<<<dim3(E / 64, (B * S) / 128), 256, 0, stream>>>(abb, wo, out);
}

// Round 5
// 403.871 us; speedup vs baseline: 1.1826x; 1.1826x over previous
//
#include <hip/hip_runtime.h>
#include <math.h>

#define B 2
#define S 1024
#define E 2048
#define H 16
#define HD 128
#define ROT 64
#define EPSN 1e-12f

using half8 = __attribute__((ext_vector_type(8))) _Float16;
using half4 = __attribute__((ext_vector_type(4))) _Float16;
using half2 = __attribute__((ext_vector_type(2))) _Float16;
using f32x4 = __attribute__((ext_vector_type(4))) float;

__device__ inline uint4 cvt_f32x8_f16x8(float4 a, float4 b) {
    half8 h;
    h[0] = (_Float16)a.x; h[1] = (_Float16)a.y; h[2] = (_Float16)a.z; h[3] = (_Float16)a.w;
    h[4] = (_Float16)b.x; h[5] = (_Float16)b.y; h[6] = (_Float16)b.z; h[7] = (_Float16)b.w;
    return *(uint4*)&h;
}

// ---------------------------------------------------------------------------
// Fused QKV NT-GEMM, convert-on-load fp32->fp16, MFMA 16x16x32_f16.
// 128x128 tile, BK=64, 256 thr (4 waves 2x2). blockIdx.z selects {wq,wk,wv}.
// LDS layout XOR-swizzled: As[m][kq ^ (m&7)] -> staging writes and frag reads
// both conflict-free (fix for R4's 4.4e7 SQ_LDS_BANK_CONFLICT).
// A-frag: lane holds A[m=lane&15][k=(lane>>4)*8+j]; C/D: row=(lane>>4)*4+r,
// col=lane&15 (verified rounds 2-4).
// ---------------------------------------------------------------------------
__global__ __launch_bounds__(256) void gemm_qkv(const float* __restrict__ hs,
                                                const float* __restrict__ wq,
                                                const float* __restrict__ wk,
                                                const float* __restrict__ wv,
                                                _Float16* __restrict__ qo,
                                                _Float16* __restrict__ ko,
                                                _Float16* __restrict__ vo) {
    __shared__ uint4 As[128][8];   // As[m][kq^(m&7)] = fp16 A[mBase+m][k0+kq*8..+7]
    __shared__ uint4 Ws[128][8];
    const float* Wp = (blockIdx.z == 0) ? wq : (blockIdx.z == 1) ? wk : wv;
    _Float16*    C  = (blockIdx.z == 0) ? qo : (blockIdx.z == 1) ? ko : vo;
    const int tid  = threadIdx.x;
    const int lane = tid & 63;
    const int wave = tid >> 6;
    const int wm   = (wave >> 1) * 64;
    const int wn   = (wave & 1) * 64;
    const int l15  = lane & 15;
    const int lq   = lane >> 4;
    const int sw   = l15 & 7;                  // XOR-swizzle term for frag reads
    const int mBase = blockIdx.y * 128;        // over B*S
    const int h     = blockIdx.x;              // head
    const int nBase = h * 128;

    f32x4 acc[4][4];
#pragma unroll
    for (int mt = 0; mt < 4; ++mt)
#pragma unroll
        for (int nt = 0; nt < 4; ++nt)
            acc[mt][nt] = (f32x4){0.f, 0.f, 0.f, 0.f};

    for (int k0 = 0; k0 < E; k0 += 64) {
#pragma unroll
        for (int j = 0; j < 4; ++j) {
            int f = tid + j * 256;              // 128 m x 8 kq
            int m = f >> 3, kq = f & 7;
            int col = kq ^ (m & 7);
            const float4* pa = (const float4*)&hs[(size_t)(mBase + m) * E + k0 + kq * 8];
            const float4* pw = (const float4*)&Wp[(size_t)(nBase + m) * E + k0 + kq * 8];
            As[m][col] = cvt_f32x8_f16x8(pa[0], pa[1]);
            Ws[m][col] = cvt_f32x8_f16x8(pw[0], pw[1]);
        }
        __syncthreads();
#pragma unroll
        for (int ks = 0; ks < 2; ++ks) {
            half8 af[4], wf[4];
#pragma unroll
            for (int t = 0; t < 4; ++t) {
                af[t] = *(const half8*)&As[wm + t * 16 + l15][(ks * 4 + lq) ^ sw];
                wf[t] = *(const half8*)&Ws[wn + t * 16 + l15][(ks * 4 + lq) ^ sw];
            }
#pragma unroll
            for (int mt = 0; mt < 4; ++mt)
#pragma unroll
                for (int nt = 0; nt < 4; ++nt)
                    acc[mt][nt] = __builtin_amdgcn_mfma_f32_16x16x32_f16(
                        af[mt], wf[nt], acc[mt][nt], 0, 0, 0);
        }
        __syncthreads();
    }

    // write (b,h,s,d) fp16
#pragma unroll
    for (int mt = 0; mt < 4; ++mt)
#pragma unroll
        for (int nt = 0; nt < 4; ++nt)
#pragma unroll
            for (int r = 0; r < 4; ++r) {
                int row = mBase + wm + mt * 16 + lq * 4 + r;  // global s in B*S
                int d   = wn + nt * 16 + l15;
                int b = row >> 10, s = row & (S - 1);
                C[(((size_t)b * H + h) * S + s) * HD + d] = (_Float16)acc[mt][nt][r];
            }
}

// ---------------------------------------------------------------------------
// Out-projection NT-GEMM: A fp16 (b,s,E), W fp32 convert-on-load, out fp32.
// 128m x 64n tile, BK=64, 256 thr -> 512 blocks. Same XOR swizzle.
// ---------------------------------------------------------------------------
__global__ __launch_bounds__(256) void gemm_out(const _Float16* __restrict__ A,
                                                const float* __restrict__ Wp,
                                                float* __restrict__ C) {
    __shared__ uint4 As[128][8];
    __shared__ uint4 Ws[64][8];
    const int tid  = threadIdx.x;
    const int lane = tid & 63;
    const int wave = tid >> 6;
    const int wm   = (wave >> 1) * 64;
    const int wn   = (wave & 1) * 32;
    const int l15  = lane & 15;
    const int lq   = lane >> 4;
    const int sw   = l15 & 7;
    const int mBase = blockIdx.y * 128;
    const int nBase = blockIdx.x * 64;

    f32x4 acc[4][2];
#pragma unroll
    for (int mt = 0; mt < 4; ++mt)
#pragma unroll
        for (int nt = 0; nt < 2; ++nt)
            acc[mt][nt] = (f32x4){0.f, 0.f, 0.f, 0.f};

    for (int k0 = 0; k0 < E; k0 += 64) {
#pragma unroll
        for (int j = 0; j < 4; ++j) {
            int f = tid + j * 256;
            int m = f >> 3, kq = f & 7;
            As[m][kq ^ (m & 7)] =
                *(const uint4*)&A[(size_t)(mBase + m) * E + k0 + kq * 8];
        }
#pragma unroll
        for (int j = 0; j < 2; ++j) {
            int f = tid + j * 256;              // 64 n x 8 kq
            int n = f >> 3, kq = f & 7;
            const float4* pw = (const float4*)&Wp[(size_t)(nBase + n) * E + k0 + kq * 8];
            Ws[n][kq ^ (n & 7)] = cvt_f32x8_f16x8(pw[0], pw[1]);
        }
        __syncthreads();
#pragma unroll
        for (int ks = 0; ks < 2; ++ks) {
            half8 af[4], wf[2];
#pragma unroll
            for (int t = 0; t < 4; ++t)
                af[t] = *(const half8*)&As[wm + t * 16 + l15][(ks * 4 + lq) ^ sw];
#pragma unroll
            for (int t = 0; t < 2; ++t)
                wf[t] = *(const half8*)&Ws[wn + t * 16 + l15][(ks * 4 + lq) ^ sw];
#pragma unroll
            for (int mt = 0; mt < 4; ++mt)
#pragma unroll
                for (int nt = 0; nt < 2; ++nt)
                    acc[mt][nt] = __builtin_amdgcn_mfma_f32_16x16x32_f16(
                        af[mt], wf[nt], acc[mt][nt], 0, 0, 0);
        }
        __syncthreads();
    }

#pragma unroll
    for (int mt = 0; mt < 4; ++mt)
#pragma unroll
        for (int nt = 0; nt < 2; ++nt)
#pragma unroll
            for (int r = 0; r < 4; ++r) {
                int row = mBase + wm + mt * 16 + lq * 4 + r;
                int col = nBase + wn + nt * 16 + l15;
                C[(size_t)row * E + col] = acc[mt][nt][r];
            }
}

// ---------------------------------------------------------------------------
// counts[b][s] = inclusive prefix of (mask==0)
// ---------------------------------------------------------------------------
__global__ __launch_bounds__(1024) void counts_kernel(const float* __restrict__ am,
                                                      float* __restrict__ counts) {
    __shared__ float buf[S];
    const int b = blockIdx.x, t = threadIdx.x;
    buf[t] = (am[b * S + t] == 0.f) ? 1.f : 0.f;
    __syncthreads();
    for (int off = 1; off < S; off <<= 1) {
        float add = (t >= off) ? buf[t - off] : 0.f;
        __syncthreads();
        buf[t] += add;
        __syncthreads();
    }
    counts[b * S + t] = buf[t];
}

// ---------------------------------------------------------------------------
// Rotary + L2 normalize + mask, in-place on fp16 (b,h,s,d).
// ---------------------------------------------------------------------------
__global__ __launch_bounds__(256) void rotary_norm(_Float16* __restrict__ qh,
                                                   _Float16* __restrict__ kh,
                                                   const float* __restrict__ am,
                                                   const int* __restrict__ pos) {
    const int wave = threadIdx.x >> 6;
    const int lane = threadIdx.x & 63;
    const int item = blockIdx.x * 4 + wave;      // < B*H*S
    const int b = item / (H * S);
    const int h = (item / S) % H;
    const int s = item % S;

    const float p = (float)pos[b * S + s];
    float co = 1.f, si = 0.f;
    if (lane < 32) {
        float ang = p * expf(-0.28782313662425574f * (float)lane); // ln(10000)/32
        sincosf(ang, &si, &co);
    }
    const float valid = (am[b * S + s] == 0.f) ? 1.f : 0.f;
    const size_t base = ((size_t)(b * H + h) * S + s) * HD;

    _Float16* bufs[2] = {qh, kh};
#pragma unroll
    for (int a = 0; a < 2; ++a) {
        _Float16* ptr = bufs[a];
        half2 xin = *(const half2*)&ptr[base + 2 * lane];
        float x0 = (float)xin[0], x1 = (float)xin[1];
        float y0, y1;
        if (lane < 32) {
            y0 = x0 * co - x1 * si;
            y1 = x1 * co + x0 * si;
        } else {
            y0 = x0;
            y1 = x1;
        }
        float ss = y0 * y0 + y1 * y1;
#pragma unroll
        for (int off = 32; off > 0; off >>= 1)
            ss += __shfl_xor(ss, off);
        float scale = valid / fmaxf(sqrtf(ss), EPSN);
        half2 xo;
        xo[0] = (_Float16)(y0 * scale);
        xo[1] = (_Float16)(y1 * scale);
        *(half2*)&ptr[base + 2 * lane] = xo;
    }
}

// ---------------------------------------------------------------------------
// vprep: v (b,h,s,d) fp16 -> scaled V^T (b,h,d,s) fp16.
// ---------------------------------------------------------------------------
__global__ __launch_bounds__(256) void vprep(const _Float16* __restrict__ v,
                                             _Float16* __restrict__ vt,
                                             const float* __restrict__ am,
                                             const float* __restrict__ counts,
                                             const float* __restrict__ nc) {
    __shared__ _Float16 T[HD][72];     // [d][s] pad 8
    __shared__ float sscale[64];
    const int bh = blockIdx.y;
    const int b = bh >> 4, h = bh & 15;
    const int s0 = blockIdx.x * 64;
    const int tid = threadIdx.x;

    if (tid < 64) {
        int s = s0 + tid;
        float sig = 1.f / (1.f + expf(-nc[h]));
        float denom = fmaxf(powf(counts[b * S + s], sig), 1.f);
        float m = (am[b * S + s] == 0.f) ? 1.f : 0.f;
        sscale[tid] = m / denom;
    }
    __syncthreads();

#pragma unroll
    for (int j = 0; j < 4; ++j) {
        int f = tid + j * 256;
        int s = f >> 4, c8 = f & 15;
        half8 x = *(const half8*)&v[((size_t)bh * S + s0 + s) * HD + c8 * 8];
        float sc = sscale[s];
#pragma unroll
        for (int i = 0; i < 8; ++i)
            T[c8 * 8 + i][s] = (_Float16)((float)x[i] * sc);
    }
    __syncthreads();

#pragma unroll
    for (int j = 0; j < 4; ++j) {
        int f = tid + j * 256;
        int d = f >> 3, c8 = f & 7;
        *(uint4*)&vt[((size_t)bh * HD + d) * S + s0 + c8 * 8] =
            *(const uint4*)&T[d][c8 * 8];
    }
}

// ---------------------------------------------------------------------------
// MFMA attention with register prefetch of the next K/V chunk.
// qh,kh: (b,h,s,d); vt: (b,h,d,s); o: (b,s,E) fp16.
// ---------------------------------------------------------------------------
__global__ __launch_bounds__(256) void attn_mfma(const _Float16* __restrict__ qh,
                                                 const _Float16* __restrict__ kh,
                                                 const _Float16* __restrict__ vt,
                                                 _Float16* __restrict__ o) {
    __shared__ _Float16 Ks[64][136];   // [key][d], +8 pad
    __shared__ _Float16 Vs[HD][72];    // [d][key], +8 pad
    __shared__ _Float16 Ps[64][72];    // [q][key], +8 pad

    const int qt = (int)gridDim.x - 1 - (int)blockIdx.x;   // heavy first
    const int bh = blockIdx.y;
    const int b = bh >> 4, h = bh & 15;
    const int tid = threadIdx.x;
    const int lane = tid & 63;
    const int w = tid >> 6;
    const int l15 = lane & 15;
    const int lq = lane >> 4;
    const int qBase = qt * 64;
    const size_t sd_base = (size_t)bh * S * HD;

    // Q A-frags in registers
    half8 qf[4];
#pragma unroll
    for (int ks = 0; ks < 4; ++ks)
        qf[ks] = *(const half8*)&qh[sd_base + (size_t)(qBase + w * 16 + l15) * HD +
                                    ks * 32 + lq * 8];

    f32x4 oacc[8];
#pragma unroll
    for (int dt = 0; dt < 8; ++dt)
        oacc[dt] = (f32x4){0.f, 0.f, 0.f, 0.f};

    const int nkc = qt + 1;
    uint4 pk[4], pv[4];
    // prefetch chunk 0
#pragma unroll
    for (int j = 0; j < 4; ++j) {
        int f = tid + j * 256;
        int rK = f >> 4, c8K = f & 15;
        int rV = f >> 3, c8V = f & 7;
        pk[j] = *(const uint4*)&kh[sd_base + (size_t)rK * HD + c8K * 8];
        pv[j] = *(const uint4*)&vt[sd_base + (size_t)rV * S + c8V * 8];
    }

    for (int kc = 0; kc < nkc; ++kc) {
        __syncthreads();   // prev-iter Ks/Vs reads complete
#pragma unroll
        for (int j = 0; j < 4; ++j) {
            int f = tid + j * 256;
            int rK = f >> 4, c8K = f & 15;
            int rV = f >> 3, c8V = f & 7;
            *(uint4*)&Ks[rK][c8K * 8] = pk[j];
            *(uint4*)&Vs[rV][c8V * 8] = pv[j];
        }
        __syncthreads();

        // issue next chunk's loads; they fly during compute below
        if (kc + 1 < nkc) {
            const int kB = (kc + 1) * 64;
#pragma unroll
            for (int j = 0; j < 4; ++j) {
                int f = tid + j * 256;
                int rK = f >> 4, c8K = f & 15;
                int rV = f >> 3, c8V = f & 7;
                pk[j] = *(const uint4*)&kh[sd_base + (size_t)(kB + rK) * HD + c8K * 8];
                pv[j] = *(const uint4*)&vt[sd_base + (size_t)rV * S + kB + c8V * 8];
            }
        }

        const int kBase = kc * 64;
        // QK^T: 4 key-tiles x 4 k-steps
        f32x4 sacc[4];
#pragma unroll
        for (int nt = 0; nt < 4; ++nt)
            sacc[nt] = (f32x4){0.f, 0.f, 0.f, 0.f};
#pragma unroll
        for (int nt = 0; nt < 4; ++nt)
#pragma unroll
            for (int ks = 0; ks < 4; ++ks) {
                half8 kf = *(const half8*)&Ks[nt * 16 + l15][ks * 32 + lq * 8];
                sacc[nt] = __builtin_amdgcn_mfma_f32_16x16x32_f16(qf[ks], kf,
                                                                  sacc[nt], 0, 0, 0);
            }

        // causal mask + P to LDS (C-layout write, wave-local rows)
#pragma unroll
        for (int nt = 0; nt < 4; ++nt)
#pragma unroll
            for (int r = 0; r < 4; ++r) {
                int qg = qBase + w * 16 + lq * 4 + r;
                int kg = kBase + nt * 16 + l15;
                float sv = (kg <= qg) ? sacc[nt][r] : 0.f;
                Ps[w * 16 + lq * 4 + r][nt * 16 + l15] = (_Float16)sv;
            }

        // PV: A-frags from Ps (wave-local), B-frags from Vs rows (= d)
        half8 pf[2];
        pf[0] = *(const half8*)&Ps[w * 16 + l15][lq * 8];
        pf[1] = *(const half8*)&Ps[w * 16 + l15][32 + lq * 8];
#pragma unroll
        for (int dt = 0; dt < 8; ++dt)
#pragma unroll
            for (int ks = 0; ks < 2; ++ks) {
                half8 vf = *(const half8*)&Vs[dt * 16 + l15][ks * 32 + lq * 8];
                oacc[dt] = __builtin_amdgcn_mfma_f32_16x16x32_f16(pf[ks], vf,
                                                                  oacc[dt], 0, 0, 0);
            }
    }

    // write O (b,s,E) fp16
#pragma unroll
    for (int dt = 0; dt < 8; ++dt)
#pragma unroll
        for (int r = 0; r < 4; ++r) {
            size_t off = (size_t)(b * S + qBase + w * 16 + lq * 4 + r) * E +
                         h * HD + dt * 16 + l15;
            o[off] = (_Float16)oacc[dt][r];
        }
}

// ---------------------------------------------------------------------------
extern "C" void kernel_launch(void* const* d_in, const int* in_sizes, int n_in,
                              void* d_out, int out_size, void* d_ws, size_t ws_size,
                              hipStream_t stream) {
    (void)in_sizes; (void)n_in; (void)out_size; (void)ws_size;
    const float* hs = (const float*)d_in[0];
    const float* wq = (const float*)d_in[1];
    const float* wk = (const float*)d_in[2];
    const float* wv = (const float*)d_in[3];
    const float* wo = (const float*)d_in[4];
    const float* nc = (const float*)d_in[5];
    const float* am = (const float*)d_in[6];
    const int*  pos = (const int*)d_in[7];
    float* out = (float*)d_out;

    const size_t act = (size_t)B * S * E;           // 4,194,304
    _Float16* qhh = (_Float16*)d_ws;                // (b,h,s,d)
    _Float16* khh = qhh + act;
    _Float16* vhh = khh + act;                      // (b,h,s,d)
    _Float16* vtt = vhh + act;                      // (b,h,d,s)
    _Float16* abb = vtt + act;                      // attn out (b,s,E)
    float* cnt = (float*)(abb + act);               // B*S floats
    // total ws: 5 * 8.39MB + 8KB ~= 42 MB

    dim3 qkvgrid(H, (B * S) / 128, 3);              // 16 x 16 x 3 = 768 blocks
    gemm_qkv<<<qkvgrid, 256, 0, stream>>>(hs, wq, wk, wv, qhh, khh, vhh);

    counts_kernel<<<B, S, 0, stream>>>(am, cnt);
    rotary_norm<<<(B * H * S) / 4, 256, 0, stream>>>(qhh, khh, am, pos);
    vprep<<<dim3(S / 64, B * H), 256, 0, stream>>>(vhh, vtt, am, cnt, nc);

    attn_mfma<<<dim3(S / 64, B * H), 256, 0, stream>>>(qhh, khh, vtt, abb);

    gemm_out<<<dim3(E / 64, (B * S) / 128), 256, 0, stream>>>(abb, wo, out);
}

// Round 6
// 391.247 us; speedup vs baseline: 1.2207x; 1.0323x over previous
//
#include <hip/hip_runtime.h>
#include <math.h>

#define B 2
#define S 1024
#define E 2048
#define H 16
#define HD 128
#define ROT 64
#define EPSN 1e-12f

using half8 = __attribute__((ext_vector_type(8))) _Float16;
using half4 = __attribute__((ext_vector_type(4))) _Float16;
using half2 = __attribute__((ext_vector_type(2))) _Float16;
using f32x4 = __attribute__((ext_vector_type(4))) float;

// async global->LDS, 16B per lane; LDS dest = wave-uniform base + lane*16
__device__ __forceinline__ void gl_lds16(const void* g, void* l) {
    __builtin_amdgcn_global_load_lds(
        (const __attribute__((address_space(1))) unsigned int*)g,
        (__attribute__((address_space(3))) unsigned int*)l, 16, 0, 0);
}

// ---------------------------------------------------------------------------
// Batched fp32 -> fp16: 5 tensors, each exactly B*S*E = E*E = 4M elements.
// ---------------------------------------------------------------------------
__global__ __launch_bounds__(256) void f2h5(const float* __restrict__ x0,
                                            const float* __restrict__ x1,
                                            const float* __restrict__ x2,
                                            const float* __restrict__ x3,
                                            const float* __restrict__ x4,
                                            _Float16* __restrict__ y0,
                                            _Float16* __restrict__ y1,
                                            _Float16* __restrict__ y2,
                                            _Float16* __restrict__ y3,
                                            _Float16* __restrict__ y4) {
    const float* xs[5] = {x0, x1, x2, x3, x4};
    _Float16*    ys[5] = {y0, y1, y2, y3, y4};
    const int t = blockIdx.y;
    const int i = blockIdx.x * 256 + threadIdx.x;
    float4 v = ((const float4*)xs[t])[i];
    half4 h;
    h[0] = (_Float16)v.x; h[1] = (_Float16)v.y;
    h[2] = (_Float16)v.z; h[3] = (_Float16)v.w;
    ((half4*)ys[t])[i] = h;
}

// ---------------------------------------------------------------------------
// Fused QKV NT-GEMM on fp16 via global_load_lds (m97 structure).
// 128x128 tile, BK=64, 256 thr (4 waves 2x2). blockIdx.z selects {wq,wk,wv}.
// LDS layout (forced by lane-scatter): [row-block rb][kq][r] uint4s,
// lane = kq*8 + r. Frag read idx = rb*64 + col*8 + r -> uniform 8 words/bank.
// A-frag: lane holds A[m=lane&15][k=(lane>>4)*8+j]; C/D: row=(lane>>4)*4+reg,
// col=lane&15 (verified rounds 2-5).
// ---------------------------------------------------------------------------
__global__ __launch_bounds__(256) void gemm_qkv(const _Float16* __restrict__ hs,
                                                const _Float16* __restrict__ wq,
                                                const _Float16* __restrict__ wk,
                                                const _Float16* __restrict__ wv,
                                                _Float16* __restrict__ qo,
                                                _Float16* __restrict__ ko,
                                                _Float16* __restrict__ vo) {
    __shared__ uint4 As_l[1024];   // 16 KB: [rb 0..15][kq 0..7][r 0..7]
    __shared__ uint4 Ws_l[1024];
    const _Float16* Wp = (blockIdx.z == 0) ? wq : (blockIdx.z == 1) ? wk : wv;
    _Float16*       C  = (blockIdx.z == 0) ? qo : (blockIdx.z == 1) ? ko : vo;
    const int tid  = threadIdx.x;
    const int lane = tid & 63;
    const int w    = tid >> 6;
    const int wm   = (w >> 1) * 64;
    const int wn   = (w & 1) * 64;
    const int l15  = lane & 15;
    const int lq   = lane >> 4;
    const int rS   = lane & 7;        // staging row within block
    const int kqS  = lane >> 3;       // staging 16B-chunk
    const int rbOf = l15 >> 3;        // frag-read row-block offset
    const int rLo  = l15 & 7;
    const int mBase = blockIdx.y * 128;        // over B*S
    const int h     = blockIdx.x;              // head
    const int nBase = h * 128;

    f32x4 acc[4][4];
#pragma unroll
    for (int mt = 0; mt < 4; ++mt)
#pragma unroll
        for (int nt = 0; nt < 4; ++nt)
            acc[mt][nt] = (f32x4){0.f, 0.f, 0.f, 0.f};

    for (int k0 = 0; k0 < E; k0 += 64) {
        __syncthreads();   // prev-iter LDS reads complete
#pragma unroll
        for (int i = 0; i < 4; ++i) {
            int rb = w * 4 + i;                // row-block 0..15
            gl_lds16(&hs[(size_t)(mBase + rb * 8 + rS) * E + k0 + kqS * 8],
                     &As_l[rb * 64]);
            gl_lds16(&Wp[(size_t)(nBase + rb * 8 + rS) * E + k0 + kqS * 8],
                     &Ws_l[rb * 64]);
        }
        __syncthreads();   // barrier drains vmcnt (compiler-inserted)

#pragma unroll
        for (int ks = 0; ks < 2; ++ks) {
            half8 af[4], wf[4];
#pragma unroll
            for (int t = 0; t < 4; ++t) {
                int rbA = ((wm + t * 16) >> 3) + rbOf;
                int rbW = ((wn + t * 16) >> 3) + rbOf;
                af[t] = *(const half8*)&As_l[rbA * 64 + (ks * 4 + lq) * 8 + rLo];
                wf[t] = *(const half8*)&Ws_l[rbW * 64 + (ks * 4 + lq) * 8 + rLo];
            }
#pragma unroll
            for (int mt = 0; mt < 4; ++mt)
#pragma unroll
                for (int nt = 0; nt < 4; ++nt)
                    acc[mt][nt] = __builtin_amdgcn_mfma_f32_16x16x32_f16(
                        af[mt], wf[nt], acc[mt][nt], 0, 0, 0);
        }
    }

    // write (b,h,s,d) fp16
#pragma unroll
    for (int mt = 0; mt < 4; ++mt)
#pragma unroll
        for (int nt = 0; nt < 4; ++nt)
#pragma unroll
            for (int r = 0; r < 4; ++r) {
                int row = mBase + wm + mt * 16 + lq * 4 + r;  // global s in B*S
                int d   = wn + nt * 16 + l15;
                int b = row >> 10, s = row & (S - 1);
                C[(((size_t)b * H + h) * S + s) * HD + d] = (_Float16)acc[mt][nt][r];
            }
}

// ---------------------------------------------------------------------------
// Out-projection NT-GEMM, fp16 via global_load_lds: A (b,s,E), W fp16, out fp32.
// 128m x 64n tile, BK=64, 256 thr -> 512 blocks.
// ---------------------------------------------------------------------------
__global__ __launch_bounds__(256) void gemm_out(const _Float16* __restrict__ A,
                                                const _Float16* __restrict__ Wp,
                                                float* __restrict__ C) {
    __shared__ uint4 As_l[1024];   // 16 row-blocks
    __shared__ uint4 Ws_l[512];    // 8 row-blocks
    const int tid  = threadIdx.x;
    const int lane = tid & 63;
    const int w    = tid >> 6;
    const int wm   = (w >> 1) * 64;
    const int wn   = (w & 1) * 32;
    const int l15  = lane & 15;
    const int lq   = lane >> 4;
    const int rS   = lane & 7;
    const int kqS  = lane >> 3;
    const int rbOf = l15 >> 3;
    const int rLo  = l15 & 7;
    const int mBase = blockIdx.y * 128;
    const int nBase = blockIdx.x * 64;

    f32x4 acc[4][2];
#pragma unroll
    for (int mt = 0; mt < 4; ++mt)
#pragma unroll
        for (int nt = 0; nt < 2; ++nt)
            acc[mt][nt] = (f32x4){0.f, 0.f, 0.f, 0.f};

    for (int k0 = 0; k0 < E; k0 += 64) {
        __syncthreads();
#pragma unroll
        for (int i = 0; i < 4; ++i) {
            int rb = w * 4 + i;
            gl_lds16(&A[(size_t)(mBase + rb * 8 + rS) * E + k0 + kqS * 8],
                     &As_l[rb * 64]);
        }
#pragma unroll
        for (int i = 0; i < 2; ++i) {
            int rb = w * 2 + i;                // 0..7
            gl_lds16(&Wp[(size_t)(nBase + rb * 8 + rS) * E + k0 + kqS * 8],
                     &Ws_l[rb * 64]);
        }
        __syncthreads();

#pragma unroll
        for (int ks = 0; ks < 2; ++ks) {
            half8 af[4], wf[2];
#pragma unroll
            for (int t = 0; t < 4; ++t) {
                int rbA = ((wm + t * 16) >> 3) + rbOf;
                af[t] = *(const half8*)&As_l[rbA * 64 + (ks * 4 + lq) * 8 + rLo];
            }
#pragma unroll
            for (int t = 0; t < 2; ++t) {
                int rbW = ((wn + t * 16) >> 3) + rbOf;
                wf[t] = *(const half8*)&Ws_l[rbW * 64 + (ks * 4 + lq) * 8 + rLo];
            }
#pragma unroll
            for (int mt = 0; mt < 4; ++mt)
#pragma unroll
                for (int nt = 0; nt < 2; ++nt)
                    acc[mt][nt] = __builtin_amdgcn_mfma_f32_16x16x32_f16(
                        af[mt], wf[nt], acc[mt][nt], 0, 0, 0);
        }
    }

#pragma unroll
    for (int mt = 0; mt < 4; ++mt)
#pragma unroll
        for (int nt = 0; nt < 2; ++nt)
#pragma unroll
            for (int r = 0; r < 4; ++r) {
                int row = mBase + wm + mt * 16 + lq * 4 + r;
                int col = nBase + wn + nt * 16 + l15;
                C[(size_t)row * E + col] = acc[mt][nt][r];
            }
}

// ---------------------------------------------------------------------------
// counts[b][s] = inclusive prefix of (mask==0)
// ---------------------------------------------------------------------------
__global__ __launch_bounds__(1024) void counts_kernel(const float* __restrict__ am,
                                                      float* __restrict__ counts) {
    __shared__ float buf[S];
    const int b = blockIdx.x, t = threadIdx.x;
    buf[t] = (am[b * S + t] == 0.f) ? 1.f : 0.f;
    __syncthreads();
    for (int off = 1; off < S; off <<= 1) {
        float add = (t >= off) ? buf[t - off] : 0.f;
        __syncthreads();
        buf[t] += add;
        __syncthreads();
    }
    counts[b * S + t] = buf[t];
}

// ---------------------------------------------------------------------------
// Rotary + L2 normalize + mask, in-place on fp16 (b,h,s,d).
// ---------------------------------------------------------------------------
__global__ __launch_bounds__(256) void rotary_norm(_Float16* __restrict__ qh,
                                                   _Float16* __restrict__ kh,
                                                   const float* __restrict__ am,
                                                   const int* __restrict__ pos) {
    const int wave = threadIdx.x >> 6;
    const int lane = threadIdx.x & 63;
    const int item = blockIdx.x * 4 + wave;      // < B*H*S
    const int b = item / (H * S);
    const int h = (item / S) % H;
    const int s = item % S;

    const float p = (float)pos[b * S + s];
    float co = 1.f, si = 0.f;
    if (lane < 32) {
        float ang = p * expf(-0.28782313662425574f * (float)lane); // ln(10000)/32
        sincosf(ang, &si, &co);
    }
    const float valid = (am[b * S + s] == 0.f) ? 1.f : 0.f;
    const size_t base = ((size_t)(b * H + h) * S + s) * HD;

    _Float16* bufs[2] = {qh, kh};
#pragma unroll
    for (int a = 0; a < 2; ++a) {
        _Float16* ptr = bufs[a];
        half2 xin = *(const half2*)&ptr[base + 2 * lane];
        float x0 = (float)xin[0], x1 = (float)xin[1];
        float y0, y1;
        if (lane < 32) {
            y0 = x0 * co - x1 * si;
            y1 = x1 * co + x0 * si;
        } else {
            y0 = x0;
            y1 = x1;
        }
        float ss = y0 * y0 + y1 * y1;
#pragma unroll
        for (int off = 32; off > 0; off >>= 1)
            ss += __shfl_xor(ss, off);
        float scale = valid / fmaxf(sqrtf(ss), EPSN);
        half2 xo;
        xo[0] = (_Float16)(y0 * scale);
        xo[1] = (_Float16)(y1 * scale);
        *(half2*)&ptr[base + 2 * lane] = xo;
    }
}

// ---------------------------------------------------------------------------
// vprep: v (b,h,s,d) fp16 -> scaled V^T (b,h,d,s) fp16.
// ---------------------------------------------------------------------------
__global__ __launch_bounds__(256) void vprep(const _Float16* __restrict__ v,
                                             _Float16* __restrict__ vt,
                                             const float* __restrict__ am,
                                             const float* __restrict__ counts,
                                             const float* __restrict__ nc) {
    __shared__ _Float16 T[HD][72];     // [d][s] pad 8
    __shared__ float sscale[64];
    const int bh = blockIdx.y;
    const int b = bh >> 4, h = bh & 15;
    const int s0 = blockIdx.x * 64;
    const int tid = threadIdx.x;

    if (tid < 64) {
        int s = s0 + tid;
        float sig = 1.f / (1.f + expf(-nc[h]));
        float denom = fmaxf(powf(counts[b * S + s], sig), 1.f);
        float m = (am[b * S + s] == 0.f) ? 1.f : 0.f;
        sscale[tid] = m / denom;
    }
    __syncthreads();

#pragma unroll
    for (int j = 0; j < 4; ++j) {
        int f = tid + j * 256;
        int s = f >> 4, c8 = f & 15;
        half8 x = *(const half8*)&v[((size_t)bh * S + s0 + s) * HD + c8 * 8];
        float sc = sscale[s];
#pragma unroll
        for (int i = 0; i < 8; ++i)
            T[c8 * 8 + i][s] = (_Float16)((float)x[i] * sc);
    }
    __syncthreads();

#pragma unroll
    for (int j = 0; j < 4; ++j) {
        int f = tid + j * 256;
        int d = f >> 3, c8 = f & 7;
        *(uint4*)&vt[((size_t)bh * HD + d) * S + s0 + c8 * 8] =
            *(const uint4*)&T[d][c8 * 8];
    }
}

// ---------------------------------------------------------------------------
// MFMA attention with register prefetch of the next K/V chunk.
// qh,kh: (b,h,s,d); vt: (b,h,d,s); o: (b,s,E) fp16.
// ---------------------------------------------------------------------------
__global__ __launch_bounds__(256) void attn_mfma(const _Float16* __restrict__ qh,
                                                 const _Float16* __restrict__ kh,
                                                 const _Float16* __restrict__ vt,
                                                 _Float16* __restrict__ o) {
    __shared__ _Float16 Ks[64][136];   // [key][d], +8 pad
    __shared__ _Float16 Vs[HD][72];    // [d][key], +8 pad
    __shared__ _Float16 Ps[64][72];    // [q][key], +8 pad

    const int qt = (int)gridDim.x - 1 - (int)blockIdx.x;   // heavy first
    const int bh = blockIdx.y;
    const int b = bh >> 4, h = bh & 15;
    const int tid = threadIdx.x;
    const int lane = tid & 63;
    const int w = tid >> 6;
    const int l15 = lane & 15;
    const int lq = lane >> 4;
    const int qBase = qt * 64;
    const size_t sd_base = (size_t)bh * S * HD;

    // Q A-frags in registers
    half8 qf[4];
#pragma unroll
    for (int ks = 0; ks < 4; ++ks)
        qf[ks] = *(const half8*)&qh[sd_base + (size_t)(qBase + w * 16 + l15) * HD +
                                    ks * 32 + lq * 8];

    f32x4 oacc[8];
#pragma unroll
    for (int dt = 0; dt < 8; ++dt)
        oacc[dt] = (f32x4){0.f, 0.f, 0.f, 0.f};

    const int nkc = qt + 1;
    uint4 pk[4], pv[4];
    // prefetch chunk 0
#pragma unroll
    for (int j = 0; j < 4; ++j) {
        int f = tid + j * 256;
        int rK = f >> 4, c8K = f & 15;
        int rV = f >> 3, c8V = f & 7;
        pk[j] = *(const uint4*)&kh[sd_base + (size_t)rK * HD + c8K * 8];
        pv[j] = *(const uint4*)&vt[sd_base + (size_t)rV * S + c8V * 8];
    }

    for (int kc = 0; kc < nkc; ++kc) {
        __syncthreads();   // prev-iter Ks/Vs reads complete
#pragma unroll
        for (int j = 0; j < 4; ++j) {
            int f = tid + j * 256;
            int rK = f >> 4, c8K = f & 15;
            int rV = f >> 3, c8V = f & 7;
            *(uint4*)&Ks[rK][c8K * 8] = pk[j];
            *(uint4*)&Vs[rV][c8V * 8] = pv[j];
        }
        __syncthreads();

        // issue next chunk's loads; they fly during compute below
        if (kc + 1 < nkc) {
            const int kB = (kc + 1) * 64;
#pragma unroll
            for (int j = 0; j < 4; ++j) {
                int f = tid + j * 256;
                int rK = f >> 4, c8K = f & 15;
                int rV = f >> 3, c8V = f & 7;
                pk[j] = *(const uint4*)&kh[sd_base + (size_t)(kB + rK) * HD + c8K * 8];
                pv[j] = *(const uint4*)&vt[sd_base + (size_t)rV * S + kB + c8V * 8];
            }
        }

        const int kBase = kc * 64;
        // QK^T: 4 key-tiles x 4 k-steps
        f32x4 sacc[4];
#pragma unroll
        for (int nt = 0; nt < 4; ++nt)
            sacc[nt] = (f32x4){0.f, 0.f, 0.f, 0.f};
#pragma unroll
        for (int nt = 0; nt < 4; ++nt)
#pragma unroll
            for (int ks = 0; ks < 4; ++ks) {
                half8 kf = *(const half8*)&Ks[nt * 16 + l15][ks * 32 + lq * 8];
                sacc[nt] = __builtin_amdgcn_mfma_f32_16x16x32_f16(qf[ks], kf,
                                                                  sacc[nt], 0, 0, 0);
            }

        // causal mask + P to LDS (C-layout write, wave-local rows)
#pragma unroll
        for (int nt = 0; nt < 4; ++nt)
#pragma unroll
            for (int r = 0; r < 4; ++r) {
                int qg = qBase + w * 16 + lq * 4 + r;
                int kg = kBase + nt * 16 + l15;
                float sv = (kg <= qg) ? sacc[nt][r] : 0.f;
                Ps[w * 16 + lq * 4 + r][nt * 16 + l15] = (_Float16)sv;
            }

        // PV: A-frags from Ps (wave-local), B-frags from Vs rows (= d)
        half8 pf[2];
        pf[0] = *(const half8*)&Ps[w * 16 + l15][lq * 8];
        pf[1] = *(const half8*)&Ps[w * 16 + l15][32 + lq * 8];
#pragma unroll
        for (int dt = 0; dt < 8; ++dt)
#pragma unroll
            for (int ks = 0; ks < 2; ++ks) {
                half8 vf = *(const half8*)&Vs[dt * 16 + l15][ks * 32 + lq * 8];
                oacc[dt] = __builtin_amdgcn_mfma_f32_16x16x32_f16(pf[ks], vf,
                                                                  oacc[dt], 0, 0, 0);
            }
    }

    // write O (b,s,E) fp16
#pragma unroll
    for (int dt = 0; dt < 8; ++dt)
#pragma unroll
        for (int r = 0; r < 4; ++r) {
            size_t off = (size_t)(b * S + qBase + w * 16 + lq * 4 + r) * E +
                         h * HD + dt * 16 + l15;
            o[off] = (_Float16)oacc[dt][r];
        }
}

// ---------------------------------------------------------------------------
extern "C" void kernel_launch(void* const* d_in, const int* in_sizes, int n_in,
                              void* d_out, int out_size, void* d_ws, size_t ws_size,
                              hipStream_t stream) {
    (void)in_sizes; (void)n_in; (void)out_size; (void)ws_size;
    const float* hs = (const float*)d_in[0];
    const float* wq = (const float*)d_in[1];
    const float* wk = (const float*)d_in[2];
    const float* wv = (const float*)d_in[3];
    const float* wo = (const float*)d_in[4];
    const float* nc = (const float*)d_in[5];
    const float* am = (const float*)d_in[6];
    const int*  pos = (const int*)d_in[7];
    float* out = (float*)d_out;

    const size_t act = (size_t)B * S * E;           // 4,194,304 (== E*E)
    _Float16* hsb = (_Float16*)d_ws;                // fp16 copies
    _Float16* wqb = hsb + act;
    _Float16* wkb = wqb + act;
    _Float16* wvb = wkb + act;
    _Float16* wob = wvb + act;
    _Float16* qhh = wob + act;                      // (b,h,s,d)
    _Float16* khh = qhh + act;
    _Float16* vhh = khh + act;                      // (b,h,s,d)
    _Float16* vtt = vhh + act;                      // (b,h,d,s)
    _Float16* abb = vtt + act;                      // attn out (b,s,E)
    float* cnt = (float*)(abb + act);               // B*S floats
    // total ws: 10 * 8.39MB + 8KB ~= 84 MB

    f2h5<<<dim3((int)(act / 4 / 256), 5), 256, 0, stream>>>(
        hs, wq, wk, wv, wo, hsb, wqb, wkb, wvb, wob);

    dim3 qkvgrid(H, (B * S) / 128, 3);              // 16 x 16 x 3 = 768 blocks
    gemm_qkv<<<qkvgrid, 256, 0, stream>>>(hsb, wqb, wkb, wvb, qhh, khh, vhh);

    counts_kernel<<<B, S, 0, stream>>>(am, cnt);
    rotary_norm<<<(B * H * S) / 4, 256, 0, stream>>>(qhh, khh, am, pos);
    vprep<<<dim3(S / 64, B * H), 256, 0, stream>>>(vhh, vtt, am, cnt, nc);

    attn_mfma<<<dim3(S / 64, B * H), 256, 0, stream>>>(qhh, khh, vtt, abb);

    gemm_out<<<dim3(E / 64, (B * S) / 128), 256, 0, stream>>>(abb, wob, out);
}

// Round 7
// 387.236 us; speedup vs baseline: 1.2334x; 1.0104x over previous
//
#include <hip/hip_runtime.h>
#include <math.h>

#define B 2
#define S 1024
#define E 2048
#define H 16
#define HD 128
#define ROT 64
#define EPSN 1e-12f

using half8 = __attribute__((ext_vector_type(8))) _Float16;
using half4 = __attribute__((ext_vector_type(4))) _Float16;
using half2 = __attribute__((ext_vector_type(2))) _Float16;
using f32x4 = __attribute__((ext_vector_type(4))) float;

// async global->LDS, 16B per lane; LDS dest = wave-uniform base + lane*16
__device__ __forceinline__ void gl_lds16(const void* g, void* l) {
    __builtin_amdgcn_global_load_lds(
        (const __attribute__((address_space(1))) unsigned int*)g,
        (__attribute__((address_space(3))) unsigned int*)l, 16, 0, 0);
}

// ---------------------------------------------------------------------------
// Batched fp32 -> fp16: 5 tensors, each exactly B*S*E = E*E = 4M elements.
// ---------------------------------------------------------------------------
__global__ __launch_bounds__(256) void f2h5(const float* __restrict__ x0,
                                            const float* __restrict__ x1,
                                            const float* __restrict__ x2,
                                            const float* __restrict__ x3,
                                            const float* __restrict__ x4,
                                            _Float16* __restrict__ y0,
                                            _Float16* __restrict__ y1,
                                            _Float16* __restrict__ y2,
                                            _Float16* __restrict__ y3,
                                            _Float16* __restrict__ y4) {
    const float* xs[5] = {x0, x1, x2, x3, x4};
    _Float16*    ys[5] = {y0, y1, y2, y3, y4};
    const int t = blockIdx.y;
    const int i = blockIdx.x * 256 + threadIdx.x;
    float4 v = ((const float4*)xs[t])[i];
    half4 h;
    h[0] = (_Float16)v.x; h[1] = (_Float16)v.y;
    h[2] = (_Float16)v.z; h[3] = (_Float16)v.w;
    ((half4*)ys[t])[i] = h;
}

// ---------------------------------------------------------------------------
// Fused QKV NT-GEMM, fp16 via global_load_lds, DOUBLE-BUFFERED K-loop.
// 128x128 tile, BK=32, 256 thr (4 waves 2x2). blockIdx.z selects {wq,wk,wv}.
// One barrier/iter; next chunk's DMA issued right after the barrier so the
// barrier's vmcnt(0) drain waits on loads that aged a full iteration.
// LDS layout per buffer: [rb(16 rows)][kq 0..3][r 0..15] uint4,
// DMA lane = kq*16 + r (16-row x 64B-contig global segments).
// A-frag: lane holds A[m=lane&15][k=(lane>>4)*8+j]; C/D: row=(lane>>4)*4+reg,
// col=lane&15 (verified rounds 2-6).
// ---------------------------------------------------------------------------
__global__ __launch_bounds__(256) void gemm_qkv(const _Float16* __restrict__ hs,
                                                const _Float16* __restrict__ wq,
                                                const _Float16* __restrict__ wk,
                                                const _Float16* __restrict__ wv,
                                                _Float16* __restrict__ qo,
                                                _Float16* __restrict__ ko,
                                                _Float16* __restrict__ vo) {
    __shared__ uint4 As_l[2][512];   // 2 x 8 KB: [rb 0..7][kq 0..3][r 0..15]
    __shared__ uint4 Ws_l[2][512];   // total 32 KB
    const _Float16* Wp = (blockIdx.z == 0) ? wq : (blockIdx.z == 1) ? wk : wv;
    _Float16*       C  = (blockIdx.z == 0) ? qo : (blockIdx.z == 1) ? ko : vo;
    const int tid  = threadIdx.x;
    const int lane = tid & 63;
    const int w    = tid >> 6;
    const int wm   = (w >> 1) * 64;
    const int wn   = (w & 1) * 64;
    const int l15  = lane & 15;
    const int lq   = lane >> 4;
    const int r16  = lane & 15;       // staging row within 16-row block
    const int kq4  = lane >> 4;       // staging 16B k-chunk (0..3)
    const int mBase = blockIdx.y * 128;        // over B*S
    const int h     = blockIdx.x;              // head
    const int nBase = h * 128;

    f32x4 acc[4][4];
#pragma unroll
    for (int mt = 0; mt < 4; ++mt)
#pragma unroll
        for (int nt = 0; nt < 4; ++nt)
            acc[mt][nt] = (f32x4){0.f, 0.f, 0.f, 0.f};

    auto stage = [&](int bf, int k0) {
#pragma unroll
        for (int i = 0; i < 2; ++i) {
            int rb = w * 2 + i;                // 16-row block 0..7
            gl_lds16(&hs[(size_t)(mBase + rb * 16 + r16) * E + k0 + kq4 * 8],
                     &As_l[bf][rb * 64]);
            gl_lds16(&Wp[(size_t)(nBase + rb * 16 + r16) * E + k0 + kq4 * 8],
                     &Ws_l[bf][rb * 64]);
        }
    };

    stage(0, 0);                                // prologue
    const int nIter = E / 32;                   // 64
    for (int it = 0; it < nIter; ++it) {
        __syncthreads();   // drains vmcnt -> buf[it&1] ready; prev-iter reads done
        if (it + 1 < nIter) stage((it + 1) & 1, (it + 1) * 32);

        const int cur = it & 1;
        half8 af[4], wf[4];
#pragma unroll
        for (int t = 0; t < 4; ++t) {
            int rbA = (wm >> 4) + t;
            int rbW = (wn >> 4) + t;
            af[t] = *(const half8*)&As_l[cur][rbA * 64 + lq * 16 + l15];
            wf[t] = *(const half8*)&Ws_l[cur][rbW * 64 + lq * 16 + l15];
        }
#pragma unroll
        for (int mt = 0; mt < 4; ++mt)
#pragma unroll
            for (int nt = 0; nt < 4; ++nt)
                acc[mt][nt] = __builtin_amdgcn_mfma_f32_16x16x32_f16(
                    af[mt], wf[nt], acc[mt][nt], 0, 0, 0);
    }

    // write (b,h,s,d) fp16
#pragma unroll
    for (int mt = 0; mt < 4; ++mt)
#pragma unroll
        for (int nt = 0; nt < 4; ++nt)
#pragma unroll
            for (int r = 0; r < 4; ++r) {
                int row = mBase + wm + mt * 16 + lq * 4 + r;  // global s in B*S
                int d   = wn + nt * 16 + l15;
                int b = row >> 10, s = row & (S - 1);
                C[(((size_t)b * H + h) * S + s) * HD + d] = (_Float16)acc[mt][nt][r];
            }
}

// ---------------------------------------------------------------------------
// Out-projection NT-GEMM, fp16 via global_load_lds, double-buffered, BK=32.
// 128m x 64n tile, 256 thr -> 512 blocks. Same structure as gemm_qkv.
// ---------------------------------------------------------------------------
__global__ __launch_bounds__(256) void gemm_out(const _Float16* __restrict__ A,
                                                const _Float16* __restrict__ Wp,
                                                float* __restrict__ C) {
    __shared__ uint4 As_l[2][512];   // 2 x 8 KB (8 row-blocks)
    __shared__ uint4 Ws_l[2][256];   // 2 x 4 KB (4 row-blocks)
    const int tid  = threadIdx.x;
    const int lane = tid & 63;
    const int w    = tid >> 6;
    const int wm   = (w >> 1) * 64;
    const int wn   = (w & 1) * 32;
    const int l15  = lane & 15;
    const int lq   = lane >> 4;
    const int r16  = lane & 15;
    const int kq4  = lane >> 4;
    const int mBase = blockIdx.y * 128;
    const int nBase = blockIdx.x * 64;

    f32x4 acc[4][2];
#pragma unroll
    for (int mt = 0; mt < 4; ++mt)
#pragma unroll
        for (int nt = 0; nt < 2; ++nt)
            acc[mt][nt] = (f32x4){0.f, 0.f, 0.f, 0.f};

    auto stage = [&](int bf, int k0) {
#pragma unroll
        for (int i = 0; i < 2; ++i) {
            int rb = w * 2 + i;
            gl_lds16(&A[(size_t)(mBase + rb * 16 + r16) * E + k0 + kq4 * 8],
                     &As_l[bf][rb * 64]);
        }
        {
            int rb = w;                        // 0..3
            gl_lds16(&Wp[(size_t)(nBase + rb * 16 + r16) * E + k0 + kq4 * 8],
                     &Ws_l[bf][rb * 64]);
        }
    };

    stage(0, 0);
    const int nIter = E / 32;                   // 64
    for (int it = 0; it < nIter; ++it) {
        __syncthreads();
        if (it + 1 < nIter) stage((it + 1) & 1, (it + 1) * 32);

        const int cur = it & 1;
        half8 af[4], wf[2];
#pragma unroll
        for (int t = 0; t < 4; ++t) {
            int rbA = (wm >> 4) + t;
            af[t] = *(const half8*)&As_l[cur][rbA * 64 + lq * 16 + l15];
        }
#pragma unroll
        for (int t = 0; t < 2; ++t) {
            int rbW = (wn >> 4) + t;
            wf[t] = *(const half8*)&Ws_l[cur][rbW * 64 + lq * 16 + l15];
        }
#pragma unroll
        for (int mt = 0; mt < 4; ++mt)
#pragma unroll
            for (int nt = 0; nt < 2; ++nt)
                acc[mt][nt] = __builtin_amdgcn_mfma_f32_16x16x32_f16(
                    af[mt], wf[nt], acc[mt][nt], 0, 0, 0);
    }

#pragma unroll
    for (int mt = 0; mt < 4; ++mt)
#pragma unroll
        for (int nt = 0; nt < 2; ++nt)
#pragma unroll
            for (int r = 0; r < 4; ++r) {
                int row = mBase + wm + mt * 16 + lq * 4 + r;
                int col = nBase + wn + nt * 16 + l15;
                C[(size_t)row * E + col] = acc[mt][nt][r];
            }
}

// ---------------------------------------------------------------------------
// Rotary + L2 normalize + mask, in-place on fp16 (b,h,s,d).
// ---------------------------------------------------------------------------
__global__ __launch_bounds__(256) void rotary_norm(_Float16* __restrict__ qh,
                                                   _Float16* __restrict__ kh,
                                                   const float* __restrict__ am,
                                                   const int* __restrict__ pos) {
    const int wave = threadIdx.x >> 6;
    const int lane = threadIdx.x & 63;
    const int item = blockIdx.x * 4 + wave;      // < B*H*S
    const int b = item / (H * S);
    const int h = (item / S) % H;
    const int s = item % S;

    const float p = (float)pos[b * S + s];
    float co = 1.f, si = 0.f;
    if (lane < 32) {
        float ang = p * expf(-0.28782313662425574f * (float)lane); // ln(10000)/32
        sincosf(ang, &si, &co);
    }
    const float valid = (am[b * S + s] == 0.f) ? 1.f : 0.f;
    const size_t base = ((size_t)(b * H + h) * S + s) * HD;

    _Float16* bufs[2] = {qh, kh};
#pragma unroll
    for (int a = 0; a < 2; ++a) {
        _Float16* ptr = bufs[a];
        half2 xin = *(const half2*)&ptr[base + 2 * lane];
        float x0 = (float)xin[0], x1 = (float)xin[1];
        float y0, y1;
        if (lane < 32) {
            y0 = x0 * co - x1 * si;
            y1 = x1 * co + x0 * si;
        } else {
            y0 = x0;
            y1 = x1;
        }
        float ss = y0 * y0 + y1 * y1;
#pragma unroll
        for (int off = 32; off > 0; off >>= 1)
            ss += __shfl_xor(ss, off);
        float scale = valid / fmaxf(sqrtf(ss), EPSN);
        half2 xo;
        xo[0] = (_Float16)(y0 * scale);
        xo[1] = (_Float16)(y1 * scale);
        *(half2*)&ptr[base + 2 * lane] = xo;
    }
}

// ---------------------------------------------------------------------------
// vprep (now also computes mask-prefix counts in-block via wave scan):
// v (b,h,s,d) fp16 -> scaled V^T (b,h,d,s) fp16,
// scale = mask / max(counts^sigmoid(nc[h]), 1).
// ---------------------------------------------------------------------------
__global__ __launch_bounds__(256) void vprep(const _Float16* __restrict__ v,
                                             _Float16* __restrict__ vt,
                                             const float* __restrict__ am,
                                             const float* __restrict__ nc) {
    __shared__ _Float16 T[HD][72];     // [d][s] pad 8
    __shared__ float sscale[64];
    const int bh = blockIdx.y;
    const int b = bh >> 4, h = bh & 15;
    const int s0 = blockIdx.x * 64;
    const int tid = threadIdx.x;

    if (tid < 64) {
        const int lane = tid;
        // prefix count of (mask==0) over am[b][0 .. s0+lane]
        float basec = 0.f;
        for (int j0 = 0; j0 < s0; j0 += 64) {
            float z = (am[b * S + j0 + lane] == 0.f) ? 1.f : 0.f;
#pragma unroll
            for (int off = 32; off > 0; off >>= 1)
                z += __shfl_xor(z, off);
            basec += z;                        // wave-uniform
        }
        float zown = (am[b * S + s0 + lane] == 0.f) ? 1.f : 0.f;
        float sc = zown;                       // inclusive wave scan
#pragma unroll
        for (int off = 1; off < 64; off <<= 1) {
            float u = __shfl_up(sc, off);
            if (lane >= off) sc += u;
        }
        float cntv = basec + sc;
        float sig = 1.f / (1.f + expf(-nc[h]));
        float denom = fmaxf(powf(cntv, sig), 1.f);
        sscale[lane] = zown / denom;           // zown doubles as the mask bit
    }
    __syncthreads();

#pragma unroll
    for (int j = 0; j < 4; ++j) {
        int f = tid + j * 256;
        int s = f >> 4, c8 = f & 15;
        half8 x = *(const half8*)&v[((size_t)bh * S + s0 + s) * HD + c8 * 8];
        float sc = sscale[s];
#pragma unroll
        for (int i = 0; i < 8; ++i)
            T[c8 * 8 + i][s] = (_Float16)((float)x[i] * sc);
    }
    __syncthreads();

#pragma unroll
    for (int j = 0; j < 4; ++j) {
        int f = tid + j * 256;
        int d = f >> 3, c8 = f & 7;
        *(uint4*)&vt[((size_t)bh * HD + d) * S + s0 + c8 * 8] =
            *(const uint4*)&T[d][c8 * 8];
    }
}

// ---------------------------------------------------------------------------
// MFMA attention with register prefetch of the next K/V chunk.
// qh,kh: (b,h,s,d); vt: (b,h,d,s); o: (b,s,E) fp16.
// ---------------------------------------------------------------------------
__global__ __launch_bounds__(256) void attn_mfma(const _Float16* __restrict__ qh,
                                                 const _Float16* __restrict__ kh,
                                                 const _Float16* __restrict__ vt,
                                                 _Float16* __restrict__ o) {
    __shared__ _Float16 Ks[64][136];   // [key][d], +8 pad
    __shared__ _Float16 Vs[HD][72];    // [d][key], +8 pad
    __shared__ _Float16 Ps[64][72];    // [q][key], +8 pad

    const int qt = (int)gridDim.x - 1 - (int)blockIdx.x;   // heavy first
    const int bh = blockIdx.y;
    const int b = bh >> 4, h = bh & 15;
    const int tid = threadIdx.x;
    const int lane = tid & 63;
    const int w = tid >> 6;
    const int l15 = lane & 15;
    const int lq = lane >> 4;
    const int qBase = qt * 64;
    const size_t sd_base = (size_t)bh * S * HD;

    // Q A-frags in registers
    half8 qf[4];
#pragma unroll
    for (int ks = 0; ks < 4; ++ks)
        qf[ks] = *(const half8*)&qh[sd_base + (size_t)(qBase + w * 16 + l15) * HD +
                                    ks * 32 + lq * 8];

    f32x4 oacc[8];
#pragma unroll
    for (int dt = 0; dt < 8; ++dt)
        oacc[dt] = (f32x4){0.f, 0.f, 0.f, 0.f};

    const int nkc = qt + 1;
    uint4 pk[4], pv[4];
    // prefetch chunk 0
#pragma unroll
    for (int j = 0; j < 4; ++j) {
        int f = tid + j * 256;
        int rK = f >> 4, c8K = f & 15;
        int rV = f >> 3, c8V = f & 7;
        pk[j] = *(const uint4*)&kh[sd_base + (size_t)rK * HD + c8K * 8];
        pv[j] = *(const uint4*)&vt[sd_base + (size_t)rV * S + c8V * 8];
    }

    for (int kc = 0; kc < nkc; ++kc) {
        __syncthreads();   // prev-iter Ks/Vs reads complete
#pragma unroll
        for (int j = 0; j < 4; ++j) {
            int f = tid + j * 256;
            int rK = f >> 4, c8K = f & 15;
            int rV = f >> 3, c8V = f & 7;
            *(uint4*)&Ks[rK][c8K * 8] = pk[j];
            *(uint4*)&Vs[rV][c8V * 8] = pv[j];
        }
        __syncthreads();

        // issue next chunk's loads; they fly during compute below
        if (kc + 1 < nkc) {
            const int kB = (kc + 1) * 64;
#pragma unroll
            for (int j = 0; j < 4; ++j) {
                int f = tid + j * 256;
                int rK = f >> 4, c8K = f & 15;
                int rV = f >> 3, c8V = f & 7;
                pk[j] = *(const uint4*)&kh[sd_base + (size_t)(kB + rK) * HD + c8K * 8];
                pv[j] = *(const uint4*)&vt[sd_base + (size_t)rV * S + kB + c8V * 8];
            }
        }

        const int kBase = kc * 64;
        // QK^T: 4 key-tiles x 4 k-steps
        f32x4 sacc[4];
#pragma unroll
        for (int nt = 0; nt < 4; ++nt)
            sacc[nt] = (f32x4){0.f, 0.f, 0.f, 0.f};
#pragma unroll
        for (int nt = 0; nt < 4; ++nt)
#pragma unroll
            for (int ks = 0; ks < 4; ++ks) {
                half8 kf = *(const half8*)&Ks[nt * 16 + l15][ks * 32 + lq * 8];
                sacc[nt] = __builtin_amdgcn_mfma_f32_16x16x32_f16(qf[ks], kf,
                                                                  sacc[nt], 0, 0, 0);
            }

        // causal mask + P to LDS (C-layout write, wave-local rows)
#pragma unroll
        for (int nt = 0; nt < 4; ++nt)
#pragma unroll
            for (int r = 0; r < 4; ++r) {
                int qg = qBase + w * 16 + lq * 4 + r;
                int kg = kBase + nt * 16 + l15;
                float sv = (kg <= qg) ? sacc[nt][r] : 0.f;
                Ps[w * 16 + lq * 4 + r][nt * 16 + l15] = (_Float16)sv;
            }

        // PV: A-frags from Ps (wave-local), B-frags from Vs rows (= d)
        half8 pf[2];
        pf[0] = *(const half8*)&Ps[w * 16 + l15][lq * 8];
        pf[1] = *(const half8*)&Ps[w * 16 + l15][32 + lq * 8];
#pragma unroll
        for (int dt = 0; dt < 8; ++dt)
#pragma unroll
            for (int ks = 0; ks < 2; ++ks) {
                half8 vf = *(const half8*)&Vs[dt * 16 + l15][ks * 32 + lq * 8];
                oacc[dt] = __builtin_amdgcn_mfma_f32_16x16x32_f16(pf[ks], vf,
                                                                  oacc[dt], 0, 0, 0);
            }
    }

    // write O (b,s,E) fp16
#pragma unroll
    for (int dt = 0; dt < 8; ++dt)
#pragma unroll
        for (int r = 0; r < 4; ++r) {
            size_t off = (size_t)(b * S + qBase + w * 16 + lq * 4 + r) * E +
                         h * HD + dt * 16 + l15;
            o[off] = (_Float16)oacc[dt][r];
        }
}

// ---------------------------------------------------------------------------
extern "C" void kernel_launch(void* const* d_in, const int* in_sizes, int n_in,
                              void* d_out, int out_size, void* d_ws, size_t ws_size,
                              hipStream_t stream) {
    (void)in_sizes; (void)n_in; (void)out_size; (void)ws_size;
    const float* hs = (const float*)d_in[0];
    const float* wq = (const float*)d_in[1];
    const float* wk = (const float*)d_in[2];
    const float* wv = (const float*)d_in[3];
    const float* wo = (const float*)d_in[4];
    const float* nc = (const float*)d_in[5];
    const float* am = (const float*)d_in[6];
    const int*  pos = (const int*)d_in[7];
    float* out = (float*)d_out;

    const size_t act = (size_t)B * S * E;           // 4,194,304 (== E*E)
    _Float16* hsb = (_Float16*)d_ws;                // fp16 copies
    _Float16* wqb = hsb + act;
    _Float16* wkb = wqb + act;
    _Float16* wvb = wkb + act;
    _Float16* wob = wvb + act;
    _Float16* qhh = wob + act;                      // (b,h,s,d)
    _Float16* khh = qhh + act;
    _Float16* vhh = khh + act;                      // (b,h,s,d)
    _Float16* vtt = vhh + act;                      // (b,h,d,s)
    _Float16* abb = vtt + act;                      // attn out (b,s,E)
    // total ws: 10 * 8.39MB ~= 84 MB

    f2h5<<<dim3((int)(act / 4 / 256), 5), 256, 0, stream>>>(
        hs, wq, wk, wv, wo, hsb, wqb, wkb, wvb, wob);

    dim3 qkvgrid(H, (B * S) / 128, 3);              // 16 x 16 x 3 = 768 blocks
    gemm_qkv<<<qkvgrid, 256, 0, stream>>>(hsb, wqb, wkb, wvb, qhh, khh, vhh);

    rotary_norm<<<(B * H * S) / 4, 256, 0, stream>>>(qhh, khh, am, pos);
    vprep<<<dim3(S / 64, B * H), 256, 0, stream>>>(vhh, vtt, am, nc);

    attn_mfma<<<dim3(S / 64, B * H), 256, 0, stream>>>(qhh, khh, vtt, abb);

    gemm_out<<<dim3(E / 64, (B * S) / 128), 256, 0, stream>>>(abb, wob, out);
}